// Round 1
// baseline (369.622 us; speedup 1.0000x reference)
//
#include <hip/hip_runtime.h>

// GaussianKDE: estimate[q] = norm/N * sum_n exp(-0.5*||features@bw - x_n||^2)
// Q=4096, N=50000, D=64, all fp32.
//
// exp(-0.5*d2) = 2^(KC*f2 + KC*x2 + LOG2E*dot), KC = -0.5*log2(e).
// Compute-bound fp32 GEMM-like kernel (no fp32 MFMA on CDNA4).

#define QCNT 4096
#define NCNT 50000
#define DDIM 64

#define BQ 128
#define BN 128
#define TQ 8
#define TN 8
#define SPLITS 16
#define NPB (NCNT / SPLITS)   // 3125 exactly
#define MAIN_THREADS 256

__device__ __constant__ const float KC_ = -0.72134752044448169f;  // -0.5*log2(e)
__device__ __constant__ const float K2_ = 1.44269504088896340f;   // log2(e)

// ---- prep: f = features @ bw, cf2[q] = KC * ||f_q||^2 -------------------
// one wave per q-row: lane d computes f[q][d]
__global__ void prep_f_kernel(const float* __restrict__ features,
                              const float* __restrict__ bw,
                              float* __restrict__ f_out,
                              float* __restrict__ cf2_out) {
    const int lane = threadIdx.x & 63;
    const int q = blockIdx.x * (blockDim.x >> 6) + (threadIdx.x >> 6);
    if (q >= QCNT) return;
    const float* frow = features + q * DDIM;
    float acc = 0.f;
#pragma unroll
    for (int k = 0; k < DDIM; ++k)
        acc = fmaf(frow[k], bw[k * DDIM + lane], acc);
    f_out[q * DDIM + lane] = acc;
    float s = acc * acc;
#pragma unroll
    for (int m = 1; m < 64; m <<= 1) s += __shfl_xor(s, m, 64);
    if (lane == 0) cf2_out[q] = -0.72134752044448169f * s;
}

// ---- prep: cx2[n] = KC * ||x_n||^2 --------------------------------------
__global__ void prep_x2_kernel(const float* __restrict__ dataset,
                               float* __restrict__ cx2_out) {
    const int n = blockIdx.x * blockDim.x + threadIdx.x;
    if (n >= NCNT) return;
    const float4* row = (const float4*)(dataset + n * DDIM);
    float s = 0.f;
#pragma unroll
    for (int j = 0; j < DDIM / 4; ++j) {
        float4 v = row[j];
        s += v.x * v.x + v.y * v.y + v.z * v.z + v.w * v.w;
    }
    cx2_out[n] = -0.72134752044448169f * s;
}

// ---- main: per (q-tile, n-split): partial[split][q] = sum_n exp2(t) -----
__global__ __launch_bounds__(MAIN_THREADS, 2)
void kde_main_kernel(const float* __restrict__ f,       // [QCNT][DDIM]
                     const float* __restrict__ cf2,     // [QCNT]
                     const float* __restrict__ dataset, // [NCNT][DDIM]
                     const float* __restrict__ cx2,     // [NCNT]
                     float* __restrict__ partial)       // [SPLITS][QCNT]
{
    __shared__ __align__(16) float lf[DDIM][BQ];   // 32 KB, f transposed
    __shared__ __align__(16) float lx[DDIM][BN];   // 32 KB, x transposed
    __shared__ float lcx2[BN];

    const int tid = threadIdx.x;
    const int qtile = blockIdx.x;           // 0..31
    const int split = blockIdx.y;           // 0..15
    const int qbase = qtile * BQ;
    const int nstart = split * NPB;
    const int nend = nstart + NPB;

    // stage f tile once: thread t loads row q=t&127, d-offset (t>>7)*4, 8 steps
    {
        const int q = tid & 127;
        const int d0 = (tid >> 7) << 2;     // 0 or 4
        const float4* src = (const float4*)(f + (size_t)(qbase + q) * DDIM);
#pragma unroll
        for (int it = 0; it < 8; ++it) {
            const int d = d0 + it * 8;
            float4 v = src[d >> 2];
            lf[d + 0][q] = v.x;
            lf[d + 1][q] = v.y;
            lf[d + 2][q] = v.z;
            lf[d + 3][q] = v.w;
        }
    }

    const int ty = tid >> 4;                // 0..15
    const int tx = tid & 15;                // 0..15
    const int q0 = ty * TQ;
    const int n0 = tx * TN;

    float cf2r[TQ];
#pragma unroll
    for (int i = 0; i < TQ; ++i) cf2r[i] = cf2[qbase + q0 + i];

    float sum[TQ];
#pragma unroll
    for (int i = 0; i < TQ; ++i) sum[i] = 0.f;

    for (int nbase = nstart; nbase < nend; nbase += BN) {
        __syncthreads();   // protect lf (first iter) / lx+lcx2 reuse (later)
        {
            const int n = tid & 127;
            const int d0 = (tid >> 7) << 2;
            const int gn = nbase + n;
            const bool ok = gn < nend;
            const float4* src = (const float4*)(dataset + (size_t)gn * DDIM);
#pragma unroll
            for (int it = 0; it < 8; ++it) {
                const int d = d0 + it * 8;
                float4 v;
                if (ok) v = src[d >> 2];
                else { v.x = 0.f; v.y = 0.f; v.z = 0.f; v.w = 0.f; }
                lx[d + 0][n] = v.x;
                lx[d + 1][n] = v.y;
                lx[d + 2][n] = v.z;
                lx[d + 3][n] = v.w;
            }
            if (tid < BN) {
                const int g2 = nbase + tid;
                lcx2[tid] = (g2 < nend) ? cx2[g2] : -3.0e38f;
            }
        }
        __syncthreads();

        float acc[TQ][TN];
#pragma unroll
        for (int i = 0; i < TQ; ++i)
#pragma unroll
            for (int j = 0; j < TN; ++j) acc[i][j] = 0.f;

#pragma unroll 4
        for (int d = 0; d < DDIM; ++d) {
            float a[TQ], b[TN];
            *(float4*)&a[0] = *(const float4*)&lf[d][q0];
            *(float4*)&a[4] = *(const float4*)&lf[d][q0 + 4];
            *(float4*)&b[0] = *(const float4*)&lx[d][n0];
            *(float4*)&b[4] = *(const float4*)&lx[d][n0 + 4];
#pragma unroll
            for (int i = 0; i < TQ; ++i)
#pragma unroll
                for (int j = 0; j < TN; ++j)
                    acc[i][j] = fmaf(a[i], b[j], acc[i][j]);
        }

        float cx2r[TN];
#pragma unroll
        for (int j = 0; j < TN; ++j) cx2r[j] = lcx2[n0 + j];

#pragma unroll
        for (int i = 0; i < TQ; ++i) {
            float s = 0.f;
#pragma unroll
            for (int j = 0; j < TN; ++j) {
                float t = fmaf(1.44269504088896340f, acc[i][j], cf2r[i]) + cx2r[j];
                s += exp2f(t);
            }
            sum[i] += s;
        }
    }

    // reduce across tx (16 lanes per q-row group)
#pragma unroll
    for (int i = 0; i < TQ; ++i) {
        float s = sum[i];
        s += __shfl_xor(s, 1, 64);
        s += __shfl_xor(s, 2, 64);
        s += __shfl_xor(s, 4, 64);
        s += __shfl_xor(s, 8, 64);
        if (tx == 0) partial[split * QCNT + qbase + q0 + i] = s;
    }
}

// ---- final: out[q] = sum_splits * norm / N ------------------------------
__global__ void reduce_kernel(const float* __restrict__ partial,
                              const float* __restrict__ norm,
                              float* __restrict__ out) {
    const int q = blockIdx.x * blockDim.x + threadIdx.x;
    if (q >= QCNT) return;
    float s = 0.f;
#pragma unroll
    for (int sp = 0; sp < SPLITS; ++sp) s += partial[sp * QCNT + q];
    out[q] = s * norm[0] * (1.0f / (float)NCNT);
}

extern "C" void kernel_launch(void* const* d_in, const int* in_sizes, int n_in,
                              void* d_out, int out_size, void* d_ws, size_t ws_size,
                              hipStream_t stream) {
    const float* features = (const float*)d_in[0];
    const float* bw       = (const float*)d_in[1];
    const float* dataset  = (const float*)d_in[2];
    const float* norm     = (const float*)d_in[3];
    float* out = (float*)d_out;

    float* ws = (float*)d_ws;
    float* f       = ws;                          // 262144 floats
    float* cf2     = ws + 262144;                 // 4096
    float* cx2     = ws + 262144 + 4096;          // 50000 (padded to 50176)
    float* partial = ws + 262144 + 4096 + 50176;  // SPLITS*QCNT = 65536

    prep_f_kernel<<<QCNT / 4, 256, 0, stream>>>(features, bw, f, cf2);
    prep_x2_kernel<<<(NCNT + 255) / 256, 256, 0, stream>>>(dataset, cx2);

    dim3 grid(QCNT / BQ, SPLITS);
    kde_main_kernel<<<grid, MAIN_THREADS, 0, stream>>>(f, cf2, dataset, cx2, partial);

    reduce_kernel<<<(QCNT + 255) / 256, 256, 0, stream>>>(partial, norm, out);
}

// Round 2
// 76.612 us; speedup vs baseline: 4.8246x; 4.8246x over previous
//
#include <hip/hip_runtime.h>

// GaussianKDE via f16 MFMA:
// estimate[q] = (norm/N) * exp2(cf2_q) * sum_n exp2( dot2(q,n) + cx2_n )
//   dot2 = sum_k (log2e * f_qk) * x_nk   (f16 MFMA, fp32 accum)
//   cf2  = -0.5*log2e*||f_q||^2 (fp32), cx2 = -0.5*log2e*||x_n||^2 (fp32)
// cx2 is folded into the MFMA C-input; cf2 applied once per q at the end.

#define QCNT 4096
#define NCNT 50000
#define DDIM 64

#define BQ 256
#define BN 64
#define SPLITS 32
#define NPB 1563            // ceil(NCNT/SPLITS); 32*1563 = 50016 >= 50000
#define NITERS 25           // ceil(NPB/BN)

typedef _Float16 half8_t __attribute__((ext_vector_type(8)));
typedef float float4_t __attribute__((ext_vector_type(4)));

#define K2F 1.44269504088896340f   // log2(e)
#define KC2 -0.72134752044448169f  // -0.5*log2(e)

// ---- prep: f = features@bw; fh = f16(K2*f); cf2 = KC2*||f||^2 ----------
__global__ void prep_f_kernel(const float* __restrict__ features,
                              const float* __restrict__ bw,
                              _Float16* __restrict__ fh,
                              float* __restrict__ cf2) {
    const int lane = threadIdx.x & 63;
    const int q = blockIdx.x * (blockDim.x >> 6) + (threadIdx.x >> 6);
    if (q >= QCNT) return;
    const float* frow = features + q * DDIM;
    float acc = 0.f;
#pragma unroll
    for (int k = 0; k < DDIM; ++k)
        acc = fmaf(frow[k], bw[k * DDIM + lane], acc);
    fh[(size_t)q * DDIM + lane] = (_Float16)(K2F * acc);
    float s = acc * acc;
#pragma unroll
    for (int m = 1; m < 64; m <<= 1) s += __shfl_xor(s, m, 64);
    if (lane == 0) cf2[q] = KC2 * s;
}

// ---- prep: cx2[n] = KC2 * ||x_n||^2 -------------------------------------
__global__ void prep_x2_kernel(const float* __restrict__ dataset,
                               float* __restrict__ cx2) {
    const int n = blockIdx.x * blockDim.x + threadIdx.x;
    if (n >= NCNT) return;
    const float4* row = (const float4*)(dataset + (size_t)n * DDIM);
    float s = 0.f;
#pragma unroll
    for (int j = 0; j < DDIM / 4; ++j) {
        float4 v = row[j];
        s += v.x * v.x + v.y * v.y + v.z * v.z + v.w * v.w;
    }
    cx2[n] = KC2 * s;
}

// ---- main: 4 waves x 64q each; BN=64 n-tile staged in LDS as f16 --------
__global__ __launch_bounds__(256, 2)
void kde_main_kernel(const _Float16* __restrict__ fh,
                     const float* __restrict__ cx2,
                     const float* __restrict__ dataset,
                     float* __restrict__ partial)
{
    // [n][k] f16 tile, row = 64 f16 = 128 B = 8 chunks of 16 B.
    // chunk swizzle: physical chunk = logical chunk ^ (n & 7)  (both sides)
    __shared__ __align__(16) _Float16 xt[BN * DDIM];

    const int tid = threadIdx.x;
    const int lane = tid & 63;
    const int w = tid >> 6;
    const int l15 = lane & 15;
    const int lh = lane >> 4;           // 0..3

    const int qbase = blockIdx.x * BQ + w * 64;
    const int nstart = blockIdx.y * NPB;
    const int nlimit = min(nstart + NPB, NCNT);

    // A fragments (f rows), resident in VGPRs for the whole kernel.
    // lane l: row = qt*16 + l15, k = kt*32 + lh*8 + [0..7]
    half8_t a[4][2];
#pragma unroll
    for (int qt = 0; qt < 4; ++qt)
#pragma unroll
        for (int kt = 0; kt < 2; ++kt)
            a[qt][kt] = *(const half8_t*)(fh + (size_t)(qbase + qt * 16 + l15) * DDIM
                                             + kt * 32 + lh * 8);

    float sum[4][4];
#pragma unroll
    for (int qt = 0; qt < 4; ++qt)
#pragma unroll
        for (int r = 0; r < 4; ++r) sum[qt][r] = 0.f;

    // staging map: thread t -> row sn = t>>2, 16-float k-chunk sk = t&3
    const int sn = tid >> 2;
    const int sk = tid & 3;
    const int c0 = (sk * 2) ^ (sn & 7);
    const int c1 = (sk * 2 + 1) ^ (sn & 7);

    for (int it = 0; it < NITERS; ++it) {
        const int nb = nstart + it * BN;
        __syncthreads();
        {   // stage fp32 -> f16 tile (reg-staged so the swizzled write is legal)
            const int ng = nb + sn;
            float4_t v0 = {0.f,0.f,0.f,0.f}, v1 = {0.f,0.f,0.f,0.f};
            float4_t v2 = {0.f,0.f,0.f,0.f}, v3 = {0.f,0.f,0.f,0.f};
            if (ng < nlimit) {
                const float4_t* src = (const float4_t*)(dataset + (size_t)ng * DDIM + sk * 16);
                v0 = src[0]; v1 = src[1]; v2 = src[2]; v3 = src[3];
            }
            half8_t h0, h1;
            h0[0]=(_Float16)v0[0]; h0[1]=(_Float16)v0[1]; h0[2]=(_Float16)v0[2]; h0[3]=(_Float16)v0[3];
            h0[4]=(_Float16)v1[0]; h0[5]=(_Float16)v1[1]; h0[6]=(_Float16)v1[2]; h0[7]=(_Float16)v1[3];
            h1[0]=(_Float16)v2[0]; h1[1]=(_Float16)v2[1]; h1[2]=(_Float16)v2[2]; h1[3]=(_Float16)v2[3];
            h1[4]=(_Float16)v3[0]; h1[5]=(_Float16)v3[1]; h1[6]=(_Float16)v3[2]; h1[7]=(_Float16)v3[3];
            *(half8_t*)(xt + sn * DDIM + c0 * 8) = h0;
            *(half8_t*)(xt + sn * DDIM + c1 * 8) = h1;
        }
        __syncthreads();

#pragma unroll
        for (int nt = 0; nt < 4; ++nt) {
            const int ng = nb + nt * 16 + l15;
            const float c2 = (ng < nlimit) ? cx2[ng] : -1.0e30f;
            const int brow = nt * 16 + l15;
            // B fragment: col = l15 (row of X), k = kt*32 + lh*8 + [0..7]
            const half8_t b0 = *(const half8_t*)(xt + brow * DDIM + ((lh      ^ (brow & 7)) * 8));
            const half8_t b1 = *(const half8_t*)(xt + brow * DDIM + (((4 + lh) ^ (brow & 7)) * 8));
            float4_t acc[4];
#pragma unroll
            for (int qt = 0; qt < 4; ++qt) {
                float4_t c = {c2, c2, c2, c2};   // fold cx2 into C-input
                acc[qt] = __builtin_amdgcn_mfma_f32_16x16x32_f16(a[qt][0], b0, c, 0, 0, 0);
                acc[qt] = __builtin_amdgcn_mfma_f32_16x16x32_f16(a[qt][1], b1, acc[qt], 0, 0, 0);
            }
#pragma unroll
            for (int qt = 0; qt < 4; ++qt)
#pragma unroll
                for (int r = 0; r < 4; ++r)
                    sum[qt][r] += __builtin_amdgcn_exp2f(acc[qt][r]);
        }
    }

    // reduce over the 16 n-columns (lanes within each lh group)
#pragma unroll
    for (int qt = 0; qt < 4; ++qt)
#pragma unroll
        for (int r = 0; r < 4; ++r) {
            float s = sum[qt][r];
            s += __shfl_xor(s, 1, 64);
            s += __shfl_xor(s, 2, 64);
            s += __shfl_xor(s, 4, 64);
            s += __shfl_xor(s, 8, 64);
            sum[qt][r] = s;
        }
    if (l15 == 0) {
        float* dst = partial + (size_t)blockIdx.y * QCNT + qbase;
#pragma unroll
        for (int qt = 0; qt < 4; ++qt)
#pragma unroll
            for (int r = 0; r < 4; ++r)
                dst[qt * 16 + lh * 4 + r] = sum[qt][r];   // C row = lh*4 + r
    }
}

// ---- final: out[q] = (sum_sp partial) * exp2(cf2[q]) * norm / N ---------
__global__ void reduce_kernel(const float* __restrict__ partial,
                              const float* __restrict__ cf2,
                              const float* __restrict__ norm,
                              float* __restrict__ out) {
    const int q = blockIdx.x * blockDim.x + threadIdx.x;
    if (q >= QCNT) return;
    float s = 0.f;
#pragma unroll
    for (int sp = 0; sp < SPLITS; ++sp) s += partial[(size_t)sp * QCNT + q];
    out[q] = s * __builtin_amdgcn_exp2f(cf2[q]) * norm[0] * (1.0f / (float)NCNT);
}

extern "C" void kernel_launch(void* const* d_in, const int* in_sizes, int n_in,
                              void* d_out, int out_size, void* d_ws, size_t ws_size,
                              hipStream_t stream) {
    const float* features = (const float*)d_in[0];
    const float* bw       = (const float*)d_in[1];
    const float* dataset  = (const float*)d_in[2];
    const float* norm     = (const float*)d_in[3];
    float* out = (float*)d_out;

    float* ws = (float*)d_ws;
    _Float16* fh   = (_Float16*)ws;                       // 4096*64 f16 = 131072 floats
    float* cf2     = ws + 131072;                         // 4096
    float* cx2     = ws + 131072 + 4096;                  // 50000 (pad 50176)
    float* partial = ws + 131072 + 4096 + 50176;          // 32*4096 = 131072
    // total 316416 floats = 1.27 MB

    prep_f_kernel<<<QCNT / 4, 256, 0, stream>>>(features, bw, fh, cf2);
    prep_x2_kernel<<<(NCNT + 255) / 256, 256, 0, stream>>>(dataset, cx2);

    dim3 grid(QCNT / BQ, SPLITS);
    kde_main_kernel<<<grid, 256, 0, stream>>>(fh, cx2, dataset, partial);

    reduce_kernel<<<(QCNT + 255) / 256, 256, 0, stream>>>(partial, cf2, norm, out);
}

// Round 3
// 72.493 us; speedup vs baseline: 5.0987x; 1.0568x over previous
//
#include <hip/hip_runtime.h>

// GaussianKDE via f16 MFMA, double-buffered global_load_lds pipeline.
// estimate[q] = (norm/N) * exp2(cf2_q) * sum_n exp2( dot2(q,n) + cx2_n )
//   dot2 = sum_k (log2e * f_qk) * x_nk   (f16 MFMA, fp32 accum)
//   cf2  = -0.5*log2e*||f_q||^2 (fp32), cx2 = -0.5*log2e*||x_n||^2 (fp32)
// xh is pre-converted f16 and PRE-SWIZZLED in global (chunk c -> c^(n&7)) so a
// linear global_load_lds copy yields the swizzled LDS layout the b-frag reads
// expect (bank-conflict-free, 0 conflicts measured in round 2).

#define QCNT 4096
#define NCNT 50000
#define DDIM 64

// fast path
#define SPLITS 64
#define NPB 832             // 13*64; SPLITS*NPB = 53248 >= 50000 (padded)
#define NROWS (SPLITS * NPB)
#define NITERS 13
#define BQ 256
#define BN 64

// fallback (round-2 proven path)
#define FSPLITS 32
#define FNPB 1563
#define FNITERS 25

typedef _Float16 half8_t __attribute__((ext_vector_type(8)));
typedef float float4_t __attribute__((ext_vector_type(4)));

#define K2F 1.44269504088896340f   // log2(e)
#define KC2 -0.72134752044448169f  // -0.5*log2(e)

typedef const __attribute__((address_space(1))) unsigned int* gas_u32;
typedef __attribute__((address_space(3))) unsigned int* las_u32;

__device__ __forceinline__ void gl16(const _Float16* g, _Float16* l) {
    // dest = wave-uniform LDS base + lane*16; src is per-lane
    __builtin_amdgcn_global_load_lds((gas_u32)(const void*)g, (las_u32)(void*)l,
                                     16, 0, 0);
}

// ---- prep: f = features@bw; fh = f16(K2*f); cf2 = KC2*||f||^2 -----------
__global__ void prep_f_kernel(const float* __restrict__ features,
                              const float* __restrict__ bw,
                              _Float16* __restrict__ fh,
                              float* __restrict__ cf2) {
    const int lane = threadIdx.x & 63;
    const int q = blockIdx.x * (blockDim.x >> 6) + (threadIdx.x >> 6);
    if (q >= QCNT) return;
    const float* frow = features + q * DDIM;
    float acc = 0.f;
#pragma unroll
    for (int k = 0; k < DDIM; ++k)
        acc = fmaf(frow[k], bw[k * DDIM + lane], acc);
    fh[(size_t)q * DDIM + lane] = (_Float16)(K2F * acc);
    float s = acc * acc;
#pragma unroll
    for (int m = 1; m < 64; m <<= 1) s += __shfl_xor(s, m, 64);
    if (lane == 0) cf2[q] = KC2 * s;
}

// ---- prep (fast): xh = swizzled f16 dataset (padded), cx2g --------------
__global__ void prep_x_fast(const float* __restrict__ dataset,
                            _Float16* __restrict__ xh,
                            float* __restrict__ cx2g) {
    const int t = blockIdx.x * blockDim.x + threadIdx.x;  // NROWS*8 threads
    const int row = t >> 3;
    const int c = t & 7;                                  // 8-float chunk
    if (row >= NROWS) return;
    float4_t v0 = {0.f, 0.f, 0.f, 0.f}, v1 = {0.f, 0.f, 0.f, 0.f};
    if (row < NCNT) {
        const float4_t* src = (const float4_t*)(dataset + (size_t)row * DDIM + c * 8);
        v0 = src[0]; v1 = src[1];
    }
    float s = v0[0]*v0[0] + v0[1]*v0[1] + v0[2]*v0[2] + v0[3]*v0[3]
            + v1[0]*v1[0] + v1[1]*v1[1] + v1[2]*v1[2] + v1[3]*v1[3];
    s += __shfl_xor(s, 1, 64);
    s += __shfl_xor(s, 2, 64);
    s += __shfl_xor(s, 4, 64);
    if (c == 0) cx2g[row] = (row < NCNT) ? KC2 * s : -3.0e38f;
    half8_t h;
    h[0] = (_Float16)v0[0]; h[1] = (_Float16)v0[1];
    h[2] = (_Float16)v0[2]; h[3] = (_Float16)v0[3];
    h[4] = (_Float16)v1[0]; h[5] = (_Float16)v1[1];
    h[6] = (_Float16)v1[2]; h[7] = (_Float16)v1[3];
    *(half8_t*)(xh + (size_t)row * DDIM + ((c ^ (row & 7)) * 8)) = h;
}

// ---- main (fast): dbuf global_load_lds pipeline, 4 blocks/CU ------------
__global__ __launch_bounds__(256, 4)
void kde_main_fast(const _Float16* __restrict__ fh,
                   const float* __restrict__ cx2g,
                   const _Float16* __restrict__ xh,
                   float* __restrict__ partial) {
    __shared__ __align__(16) _Float16 xt[2][BN * DDIM];   // 2 x 8 KB
    __shared__ float lcx2[NPB];                           // 3.25 KB

    const int tid = threadIdx.x;
    const int lane = tid & 63;
    const int w = tid >> 6;
    const int l15 = lane & 15;
    const int lh = lane >> 4;

    // bijective XCD swizzle: XCD x owns splits 8x..8x+7 (852 KB -> L2-resident)
    const int bid = blockIdx.x;                 // 0..1023
    const int xcd = bid & 7;
    const int j = bid >> 3;                     // 0..127
    const int split = xcd * 8 + (j & 7);        // 0..63
    const int qtile = j >> 3;                   // 0..15

    const int qbase = qtile * BQ + w * 64;
    const _Float16* xslice = xh + (size_t)split * NPB * DDIM;
    const float* cxs = cx2g + split * NPB;

    // A fragments resident in VGPRs: lane l -> row qt*16+l15, k = kt*32+lh*8
    half8_t a[4][2];
#pragma unroll
    for (int qt = 0; qt < 4; ++qt)
#pragma unroll
        for (int kt = 0; kt < 2; ++kt)
            a[qt][kt] = *(const half8_t*)(fh + (size_t)(qbase + qt * 16 + l15) * DDIM
                                             + kt * 32 + lh * 8);

    // persistent cx2 tile for all 13 iterations
    for (int i = tid; i < NPB; i += 256) lcx2[i] = cxs[i];

    float sum[4][4];
#pragma unroll
    for (int qt = 0; qt < 4; ++qt)
#pragma unroll
        for (int r = 0; r < 4; ++r) sum[qt][r] = 0.f;

    // stage tile `it` into buffer bsel: 2 global_load_lds_dwordx4 per wave
#define STAGE(it_, bsel_)                                                     \
    {                                                                         \
        const _Float16* gsrc_ = xslice + (size_t)(it_) * BN * DDIM;           \
        _Float16* dst_ = &xt[bsel_][0];                                       \
        _Pragma("unroll")                                                     \
        for (int jj = 0; jj < 2; ++jj) {                                      \
            const int ci = w * 128 + jj * 64 + lane;                          \
            gl16(gsrc_ + ci * 8, dst_ + (w * 128 + jj * 64) * 8);             \
        }                                                                     \
    }

    STAGE(0, 0);
    __syncthreads();   // full drain once: lcx2 writes + tile-0 loads

    int cur = 0;
    for (int it = 0; it < NITERS; ++it) {
        if (it + 1 < NITERS) STAGE(it + 1, cur ^ 1);   // prefetch next tile
        const _Float16* xb = &xt[cur][0];
#pragma unroll
        for (int nt = 0; nt < 4; ++nt) {
            const int brow = nt * 16 + l15;
            const float c2 = lcx2[it * BN + brow];     // broadcast across lh
            const half8_t b0 = *(const half8_t*)(xb + brow * DDIM + ((lh ^ (brow & 7)) * 8));
            const half8_t b1 = *(const half8_t*)(xb + brow * DDIM + (((4 + lh) ^ (brow & 7)) * 8));
#pragma unroll
            for (int qt = 0; qt < 4; ++qt) {
                float4_t c = {c2, c2, c2, c2};         // fold cx2 into C-input
                float4_t acc = __builtin_amdgcn_mfma_f32_16x16x32_f16(a[qt][0], b0, c, 0, 0, 0);
                acc = __builtin_amdgcn_mfma_f32_16x16x32_f16(a[qt][1], b1, acc, 0, 0, 0);
#pragma unroll
                for (int r = 0; r < 4; ++r)
                    sum[qt][r] += __builtin_amdgcn_exp2f(acc[r]);
            }
        }
        asm volatile("s_waitcnt vmcnt(0)" ::: "memory");  // prefetch landed
        __builtin_amdgcn_s_barrier();                      // raw: no full drain
        asm volatile("" ::: "memory");
        cur ^= 1;
    }

    // reduce over the 16 n-columns
#pragma unroll
    for (int qt = 0; qt < 4; ++qt)
#pragma unroll
        for (int r = 0; r < 4; ++r) {
            float s = sum[qt][r];
            s += __shfl_xor(s, 1, 64);
            s += __shfl_xor(s, 2, 64);
            s += __shfl_xor(s, 4, 64);
            s += __shfl_xor(s, 8, 64);
            sum[qt][r] = s;
        }
    if (l15 == 0) {
        float* dst = partial + (size_t)split * QCNT + qbase;
#pragma unroll
        for (int qt = 0; qt < 4; ++qt)
#pragma unroll
            for (int r = 0; r < 4; ++r)
                dst[qt * 16 + lh * 4 + r] = sum[qt][r];   // C row = lh*4 + r
    }
#undef STAGE
}

// ======================= fallback path (round-2, proven) ==================
__global__ void prep_x2_kernel(const float* __restrict__ dataset,
                               float* __restrict__ cx2) {
    const int n = blockIdx.x * blockDim.x + threadIdx.x;
    if (n >= NCNT) return;
    const float4* row = (const float4*)(dataset + (size_t)n * DDIM);
    float s = 0.f;
#pragma unroll
    for (int jq = 0; jq < DDIM / 4; ++jq) {
        float4 v = row[jq];
        s += v.x * v.x + v.y * v.y + v.z * v.z + v.w * v.w;
    }
    cx2[n] = KC2 * s;
}

__global__ __launch_bounds__(256, 2)
void kde_main_fb(const _Float16* __restrict__ fh,
                 const float* __restrict__ cx2,
                 const float* __restrict__ dataset,
                 float* __restrict__ partial) {
    __shared__ __align__(16) _Float16 xt[BN * DDIM];
    const int tid = threadIdx.x;
    const int lane = tid & 63;
    const int w = tid >> 6;
    const int l15 = lane & 15;
    const int lh = lane >> 4;
    const int qbase = blockIdx.x * BQ + w * 64;
    const int nstart = blockIdx.y * FNPB;
    const int nlimit = min(nstart + FNPB, NCNT);

    half8_t a[4][2];
#pragma unroll
    for (int qt = 0; qt < 4; ++qt)
#pragma unroll
        for (int kt = 0; kt < 2; ++kt)
            a[qt][kt] = *(const half8_t*)(fh + (size_t)(qbase + qt * 16 + l15) * DDIM
                                             + kt * 32 + lh * 8);
    float sum[4][4];
#pragma unroll
    for (int qt = 0; qt < 4; ++qt)
#pragma unroll
        for (int r = 0; r < 4; ++r) sum[qt][r] = 0.f;

    const int sn = tid >> 2;
    const int sk = tid & 3;
    const int c0 = (sk * 2) ^ (sn & 7);
    const int c1 = (sk * 2 + 1) ^ (sn & 7);

    for (int it = 0; it < FNITERS; ++it) {
        const int nb = nstart + it * BN;
        __syncthreads();
        {
            const int ng = nb + sn;
            float4_t v0 = {0.f,0.f,0.f,0.f}, v1 = {0.f,0.f,0.f,0.f};
            float4_t v2 = {0.f,0.f,0.f,0.f}, v3 = {0.f,0.f,0.f,0.f};
            if (ng < nlimit) {
                const float4_t* src = (const float4_t*)(dataset + (size_t)ng * DDIM + sk * 16);
                v0 = src[0]; v1 = src[1]; v2 = src[2]; v3 = src[3];
            }
            half8_t h0, h1;
            h0[0]=(_Float16)v0[0]; h0[1]=(_Float16)v0[1]; h0[2]=(_Float16)v0[2]; h0[3]=(_Float16)v0[3];
            h0[4]=(_Float16)v1[0]; h0[5]=(_Float16)v1[1]; h0[6]=(_Float16)v1[2]; h0[7]=(_Float16)v1[3];
            h1[0]=(_Float16)v2[0]; h1[1]=(_Float16)v2[1]; h1[2]=(_Float16)v2[2]; h1[3]=(_Float16)v2[3];
            h1[4]=(_Float16)v3[0]; h1[5]=(_Float16)v3[1]; h1[6]=(_Float16)v3[2]; h1[7]=(_Float16)v3[3];
            *(half8_t*)(xt + sn * DDIM + c0 * 8) = h0;
            *(half8_t*)(xt + sn * DDIM + c1 * 8) = h1;
        }
        __syncthreads();
#pragma unroll
        for (int nt = 0; nt < 4; ++nt) {
            const int ng = nb + nt * 16 + l15;
            const float c2 = (ng < nlimit) ? cx2[ng] : -1.0e30f;
            const int brow = nt * 16 + l15;
            const half8_t b0 = *(const half8_t*)(xt + brow * DDIM + ((lh ^ (brow & 7)) * 8));
            const half8_t b1 = *(const half8_t*)(xt + brow * DDIM + (((4 + lh) ^ (brow & 7)) * 8));
#pragma unroll
            for (int qt = 0; qt < 4; ++qt) {
                float4_t c = {c2, c2, c2, c2};
                float4_t acc = __builtin_amdgcn_mfma_f32_16x16x32_f16(a[qt][0], b0, c, 0, 0, 0);
                acc = __builtin_amdgcn_mfma_f32_16x16x32_f16(a[qt][1], b1, acc, 0, 0, 0);
#pragma unroll
                for (int r = 0; r < 4; ++r)
                    sum[qt][r] += __builtin_amdgcn_exp2f(acc[r]);
            }
        }
    }
#pragma unroll
    for (int qt = 0; qt < 4; ++qt)
#pragma unroll
        for (int r = 0; r < 4; ++r) {
            float s = sum[qt][r];
            s += __shfl_xor(s, 1, 64);
            s += __shfl_xor(s, 2, 64);
            s += __shfl_xor(s, 4, 64);
            s += __shfl_xor(s, 8, 64);
            sum[qt][r] = s;
        }
    if (l15 == 0) {
        float* dst = partial + (size_t)blockIdx.y * QCNT + qbase;
#pragma unroll
        for (int qt = 0; qt < 4; ++qt)
#pragma unroll
            for (int r = 0; r < 4; ++r)
                dst[qt * 16 + lh * 4 + r] = sum[qt][r];
    }
}

// ---- final: out[q] = (sum_sp partial) * exp2(cf2[q]) * norm / N ---------
__global__ void reduce_kernel(const float* __restrict__ partial,
                              const float* __restrict__ cf2,
                              const float* __restrict__ norm,
                              float* __restrict__ out, int splits) {
    const int q = blockIdx.x * blockDim.x + threadIdx.x;
    if (q >= QCNT) return;
    float s = 0.f;
    for (int sp = 0; sp < splits; ++sp) s += partial[(size_t)sp * QCNT + q];
    out[q] = s * __builtin_amdgcn_exp2f(cf2[q]) * norm[0] * (1.0f / (float)NCNT);
}

extern "C" void kernel_launch(void* const* d_in, const int* in_sizes, int n_in,
                              void* d_out, int out_size, void* d_ws, size_t ws_size,
                              hipStream_t stream) {
    const float* features = (const float*)d_in[0];
    const float* bw       = (const float*)d_in[1];
    const float* dataset  = (const float*)d_in[2];
    const float* norm     = (const float*)d_in[3];
    float* out = (float*)d_out;
    float* ws = (float*)d_ws;

    // fast-path ws layout (floats): xh 1703936 | fh 131072 | cf2 4096 |
    // cx2g 53248 | partial 262144  => 8.62 MB
    const size_t NEED = (size_t)(1703936 + 131072 + 4096 + 53248 + 262144) * 4;

    if (ws_size >= NEED) {
        _Float16* xh = (_Float16*)ws;
        _Float16* fh = (_Float16*)(ws + 1703936);
        float* cf2     = ws + 1703936 + 131072;
        float* cx2g    = cf2 + 4096;
        float* partial = cx2g + 53248;

        prep_f_kernel<<<QCNT / 4, 256, 0, stream>>>(features, bw, fh, cf2);
        prep_x_fast<<<(NROWS * 8) / 256, 256, 0, stream>>>(dataset, xh, cx2g);
        kde_main_fast<<<16 * SPLITS, 256, 0, stream>>>(fh, cx2g, xh, partial);
        reduce_kernel<<<QCNT / 256, 256, 0, stream>>>(partial, cf2, norm, out, SPLITS);
    } else {
        _Float16* fh = (_Float16*)ws;                 // 131072 floats
        float* cf2     = ws + 131072;
        float* cx2     = ws + 131072 + 4096;
        float* partial = ws + 131072 + 4096 + 50176;  // FSPLITS*QCNT

        prep_f_kernel<<<QCNT / 4, 256, 0, stream>>>(features, bw, fh, cf2);
        prep_x2_kernel<<<(NCNT + 255) / 256, 256, 0, stream>>>(dataset, cx2);
        dim3 grid(QCNT / BQ, FSPLITS);
        kde_main_fb<<<grid, 256, 0, stream>>>(fh, cx2, dataset, partial);
        reduce_kernel<<<QCNT / 256, 256, 0, stream>>>(partial, cf2, norm, out, FSPLITS);
    }
}